// Round 15
// baseline (145.336 us; speedup 1.0000x reference)
//
#include <hip/hip_runtime.h>
#include <cstddef>
#include <cstdint>

#define S_LEN 2048
#define D_DIM 512
#define NHEAD 4
#define DHEAD 128
#define BH_CNT 16
#define SCALE_QK 0.08838834764831845f

typedef _Float16 f16;
typedef _Float16 f16x8 __attribute__((ext_vector_type(8)));
typedef float f32x16 __attribute__((ext_vector_type(16)));

__device__ __forceinline__ unsigned pkh(float a, float b) {
  auto r = __builtin_amdgcn_cvt_pkrtz(a, b);   // __fp16 ext_vector_type(2)
  return __builtin_bit_cast(unsigned, r);
}

// ---------------- Kernel 1: gate preactivations ----------------
__global__ __launch_bounds__(256) void gate_kernel(
    const float* __restrict__ q, const float* __restrict__ k, const float* __restrict__ v,
    const float* __restrict__ Wi, const float* __restrict__ bi,
    const float* __restrict__ Wf, const float* __restrict__ bf,
    float* __restrict__ ipre, float* __restrict__ fpre)
{
  const int wave = threadIdx.x >> 6;
  const int lane = threadIdx.x & 63;
  const int pos  = blockIdx.x * 4 + wave;
  const int b = pos >> 11;
  const int s = pos & 2047;
  const float* qp = q + (size_t)pos * D_DIM;
  const float* kp = k + (size_t)pos * D_DIM;
  const float* vp = v + (size_t)pos * D_DIM;

  float acc[8] = {0.f,0.f,0.f,0.f,0.f,0.f,0.f,0.f};
  #pragma unroll
  for (int j = 0; j < 24; ++j) {
    int e = lane + (j << 6);
    float x;
    if (e < 512)       x = qp[e];
    else if (e < 1024) x = kp[e - 512];
    else               x = vp[e - 1024];
    #pragma unroll
    for (int h = 0; h < 4; ++h) {
      acc[h]     = fmaf(x, Wi[h * 1536 + e], acc[h]);
      acc[4 + h] = fmaf(x, Wf[h * 1536 + e], acc[4 + h]);
    }
  }
  #pragma unroll
  for (int off = 32; off > 0; off >>= 1) {
    #pragma unroll
    for (int a = 0; a < 8; ++a) acc[a] += __shfl_down(acc[a], off);
  }
  if (lane == 0) {
    #pragma unroll
    for (int h = 0; h < 4; ++h) {
      ipre[(size_t)(b * 4 + h) * S_LEN + s] = acc[h] + bi[h];
      fpre[(size_t)(b * 4 + h) * S_LEN + s] = acc[4 + h] + bf[h];
    }
  }
}

// ---------------- Kernel 2: single-pass register scans ----------------
__global__ __launch_bounds__(256) void scan_kernel(
    const float* __restrict__ ipre, const float* __restrict__ fpre,
    float* __restrict__ g_out, float* __restrict__ M_out,
    float* __restrict__ bsum_out, float* __restrict__ Gt_out)
{
  __shared__ float wsh[8];
  const int bh = blockIdx.x;
  const int tid = threadIdx.x, lane = tid & 63, wv = tid >> 6;
  const int base = tid * 8;
  const float* fp = fpre + (size_t)bh * S_LEN;
  const float* ip = ipre + (size_t)bh * S_LEN;

  float x[8], ls[8];
  float4 a0 = *(const float4*)(fp + base), a1 = *(const float4*)(fp + base + 4);
  x[0]=a0.x; x[1]=a0.y; x[2]=a0.z; x[3]=a0.w;
  x[4]=a1.x; x[5]=a1.y; x[6]=a1.z; x[7]=a1.w;
  float run = 0.f;
  #pragma unroll
  for (int i = 0; i < 8; ++i) {
    float lsv = fminf(x[i], 0.f) - log1pf(expf(-fabsf(x[i])));
    run += lsv; ls[i] = run;
  }
  float sc = run;
  #pragma unroll
  for (int off = 1; off < 64; off <<= 1) {
    float o = __shfl_up(sc, off);
    if (lane >= off) sc += o;
  }
  if (lane == 63) wsh[wv] = sc;
  __syncthreads();
  float woff = 0.f;
  #pragma unroll
  for (int u = 0; u < 4; ++u) if (u < wv) woff += wsh[u];
  const float ex = woff + (sc - run);

  float4 i0 = *(const float4*)(ip + base), i1 = *(const float4*)(ip + base + 4);
  float iv[8];
  iv[0]=i0.x; iv[1]=i0.y; iv[2]=i0.z; iv[3]=i0.w;
  iv[4]=i1.x; iv[5]=i1.y; iv[6]=i1.z; iv[7]=i1.w;
  float g[8], bc[8], pm[8];
  float runm = -3.0e38f;
  #pragma unroll
  for (int i = 0; i < 8; ++i) {
    bc[i] = ex + ls[i];
    g[i] = iv[i] - bc[i];
    runm = fmaxf(runm, g[i]);
    pm[i] = runm;
  }
  *(float4*)(bsum_out + (size_t)bh * S_LEN + base)     = make_float4(bc[0],bc[1],bc[2],bc[3]);
  *(float4*)(bsum_out + (size_t)bh * S_LEN + base + 4) = make_float4(bc[4],bc[5],bc[6],bc[7]);
  *(float4*)(g_out + (size_t)bh * S_LEN + base)        = make_float4(g[0],g[1],g[2],g[3]);
  *(float4*)(g_out + (size_t)bh * S_LEN + base + 4)    = make_float4(g[4],g[5],g[6],g[7]);

  float t8 = runm;
  t8 = fmaxf(t8, __shfl_xor(t8, 1));
  t8 = fmaxf(t8, __shfl_xor(t8, 2));
  t8 = fmaxf(t8, __shfl_xor(t8, 4));
  if ((tid & 7) == 0) Gt_out[bh * 32 + (tid >> 3)] = t8;

  float scm = runm;
  #pragma unroll
  for (int off = 1; off < 64; off <<= 1) {
    float o = __shfl_up(scm, off);
    if (lane >= off) scm = fmaxf(scm, o);
  }
  if (lane == 63) wsh[4 + wv] = scm;
  __syncthreads();
  float wmo = -3.0e38f;
  #pragma unroll
  for (int u = 0; u < 4; ++u) if (u < wv) wmo = fmaxf(wmo, wsh[4 + u]);
  float prev = __shfl_up(scm, 1);
  if (lane == 0) prev = -3.0e38f;
  const float exm = fmaxf(wmo, prev);
  float M[8];
  #pragma unroll
  for (int i = 0; i < 8; ++i) M[i] = fmaxf(exm, pm[i]);
  *(float4*)(M_out + (size_t)bh * S_LEN + base)     = make_float4(M[0],M[1],M[2],M[3]);
  *(float4*)(M_out + (size_t)bh * S_LEN + base + 4) = make_float4(M[4],M[5],M[6],M[7]);
}

// head-complementary bh pairing per XCD slot
__device__ __forceinline__ int pairA(int x) { return (x >> 1) * 4 + (x & 1); }
__device__ __forceinline__ int pairB(int x) { return (x >> 1) * 4 + 3 - (x & 1); }

// ---------------- Kernel 3: fp16 K/V conversion, fragment-linear, XCD-matched
__global__ __launch_bounds__(256) void convert_kernel(
    const float* __restrict__ k, const float* __restrict__ v,
    const float* __restrict__ g_arr, const float* __restrict__ Gt_arr,
    char* __restrict__ khat, char* __restrict__ vT)
{
  const int x = blockIdx.x, y = blockIdx.y;
  const int bh = (y < 32) ? pairA(x) : pairB(x);
  const int kt = (y < 32) ? y : (y - 32);
  const int b = bh >> 2, hh = bh & 3;
  const int tid = threadIdx.x;
  const size_t tb = (size_t)(bh * 32 + kt) * 16384;
  char* ktile = khat + tb;
  char* vtile = vT + tb;
  const float Gtv = Gt_arr[bh * 32 + kt];

  {
    const int dc8 = tid & 15;
    const int s4  = tid >> 4;
    const int ks = dc8 >> 1, hi = dc8 & 1;
    #pragma unroll
    for (int jj = 0; jj < 4; ++jj) {
      const int s = s4 + 16 * jj;
      const int sg = kt * 64 + s;
      const float cf = __expf(g_arr[(size_t)bh * S_LEN + sg] - Gtv);
      const int unit = (((s >> 5) * 8 + ks) * 2 + hi) * 32 + (s & 31);
      const float* kr = k + ((size_t)(b * S_LEN + sg)) * D_DIM + hh * DHEAD + dc8 * 8;
      float4 x0 = *(const float4*)kr;
      float4 x1 = *(const float4*)(kr + 4);
      uint4 u;
      u.x = pkh(x0.x * cf, x0.y * cf);
      u.y = pkh(x0.z * cf, x0.w * cf);
      u.z = pkh(x1.x * cf, x1.y * cf);
      u.w = pkh(x1.z * cf, x1.w * cf);
      *(uint4*)(ktile + unit * 16) = u;
    }
  }
  {
    const int d   = tid & 127;
    const int scg = tid >> 7;
    const int df = d >> 5, lo = d & 31;
    #pragma unroll
    for (int jj = 0; jj < 4; ++jj) {
      const int sc8 = scg + 2 * jj;
      const int c = sc8 >> 1, hi = sc8 & 1;
      const float* vr = v + ((size_t)(b * S_LEN + kt * 64 + sc8 * 8)) * D_DIM + hh * DHEAD + d;
      float vv[8];
      #pragma unroll
      for (int t = 0; t < 8; ++t) vv[t] = vr[(size_t)t * D_DIM];
      uint4 u;
      u.x = pkh(vv[0], vv[1]); u.y = pkh(vv[2], vv[3]);
      u.z = pkh(vv[4], vv[5]); u.w = pkh(vv[6], vv[7]);
      const int unit = ((df * 4 + c) * 2 + hi) * 32 + lo;
      *(uint4*)(vtile + unit * 16) = u;
    }
  }
}

#define MFMA_(a, b, c) __builtin_amdgcn_mfma_f32_32x32x16_f16(__builtin_bit_cast(f16x8, a), (b), (c), 0, 0, 0)

// ---------------- Kernel 4: 64-row-tile attention, per-XCD work queue --------
// 512 blocks (2/CU), launch_bounds(256,2): 2 waves/SIMD TLP, 220 VGPR fits.
// Wave w = s-quarter of the 128-kt step x all 64 t (2 t-blocks).
// K and V each read once per block-step: 64KB/block-step for 128 MFMAs.
// Q frags built from fp32 q directly (once per item). Heavy-first atomic queue.
__global__ __launch_bounds__(256, 2) void attn_kernel(
    const float* __restrict__ q, const char* __restrict__ khat, const char* __restrict__ vT,
    const float* __restrict__ M_arr, const float* __restrict__ bs_arr,
    const float* __restrict__ Gt_arr,
    const float* __restrict__ ln_w, const float* __restrict__ ln_b,
    float* __restrict__ out, int* __restrict__ qctr)
{
  __shared__ float cb[16704];         // 2x8192 h-dump + rowsum slots
  __shared__ int item_s;
  const int xcd = blockIdx.x;         // 0..7
  const int tid = threadIdx.x;
  const int w = tid >> 6, lane = tid & 63, lo = lane & 31, hi = lane >> 5;
  const int s64 = w >> 1, s32 = w & 1;
  const int lb16 = (hi * 32 + lo) * 16;

  for (;;) {
    if (tid == 0) item_s = atomicAdd(&qctr[xcd], 1);
    __syncthreads();
    const int item = item_s;
    __syncthreads();
    if (item >= 64) break;
    const int bh = (item & 1) ? pairB(xcd) : pairA(xcd);
    const int j  = 31 - (item >> 1);      // 64-row tile, heavy first
    const int b = bh >> 2, hh = bh & 3;

    const char* gk = khat + (size_t)bh * 524288;
    const char* gv = vT   + (size_t)bh * 524288;
    const float* Mb  = M_arr  + (size_t)bh * S_LEN;
    const float* bsb = bs_arr + (size_t)bh * S_LEN;
    const float GtReg = Gt_arr[bh * 32 + lo];

    const int tg0 = 64 * j + lo, tg1 = tg0 + 32;
    const float Mt0 = Mb[tg0], Mt1 = Mb[tg1];
    const float em0 = __expf(-(bsb[tg0] + Mt0));
    const float em1 = __expf(-(bsb[tg1] + Mt1));
    const float M0 = Mb[64 * j];
    const int ktLast = j >> 1;

    // ballot-based skip start
    int kts;
    {
      float ga = __shfl(GtReg, 2 * (lane & 15));
      float gb2 = __shfl(GtReg, 2 * (lane & 15) + 1);
      bool live = (lane < 16) && ((lane & 15) <= ktLast) &&
                  (fmaxf(ga, gb2) >= M0 - 25.f);
      unsigned long long mask = __ballot(live);
      kts = mask ? (__ffsll((long long)mask) - 1) : ktLast;
    }

    // Q fragments for both t-blocks, straight from fp32 q (once per item)
    f16x8 qf0[8], qf1[8];
    {
      const float* qr0 = q + ((size_t)(b * S_LEN + tg0)) * D_DIM + hh * DHEAD;
      const float* qr1 = q + ((size_t)(b * S_LEN + tg1)) * D_DIM + hh * DHEAD;
      #pragma unroll
      for (int ks = 0; ks < 8; ++ks) {
        const int d0 = ks * 16 + hi * 8;
        float4 x0 = *(const float4*)(qr0 + d0);
        float4 x1 = *(const float4*)(qr0 + d0 + 4);
        uint4 u;
        u.x = pkh(x0.x * SCALE_QK, x0.y * SCALE_QK);
        u.y = pkh(x0.z * SCALE_QK, x0.w * SCALE_QK);
        u.z = pkh(x1.x * SCALE_QK, x1.y * SCALE_QK);
        u.w = pkh(x1.z * SCALE_QK, x1.w * SCALE_QK);
        qf0[ks] = __builtin_bit_cast(f16x8, u);
        float4 y0 = *(const float4*)(qr1 + d0);
        float4 y1 = *(const float4*)(qr1 + d0 + 4);
        uint4 u2;
        u2.x = pkh(y0.x * SCALE_QK, y0.y * SCALE_QK);
        u2.y = pkh(y0.z * SCALE_QK, y0.w * SCALE_QK);
        u2.z = pkh(y1.x * SCALE_QK, y1.y * SCALE_QK);
        u2.w = pkh(y1.z * SCALE_QK, y1.w * SCALE_QK);
        qf1[ks] = __builtin_bit_cast(f16x8, u2);
      }
    }

    f32x16 h0[4] = {{},{},{},{}};   // t-block 0, d-blocks 0..3
    f32x16 h1[4] = {{},{},{},{}};   // t-block 1
    float rowsum0 = 0.f, rowsum1 = 0.f;

    for (int kt = kts; kt <= ktLast; ++kt) {
      const char* kbp = gk + (size_t)(2 * kt + s64) * 16384 + s32 * 8192 + lb16;
      uint4 kf[8];
      #pragma unroll
      for (int ks = 0; ks < 8; ++ks) kf[ks] = *(const uint4*)(kbp + ks * 1024);
      const char* vbp = gv + (size_t)(2 * kt + s64) * 16384 + 2 * s32 * 1024 + lb16;
      uint4 vf[8];
      #pragma unroll
      for (int df = 0; df < 4; ++df) {
        vf[df * 2 + 0] = *(const uint4*)(vbp + (df * 4 + 0) * 1024);
        vf[df * 2 + 1] = *(const uint4*)(vbp + (df * 4 + 1) * 1024);
      }

      const float Gtv = __shfl(GtReg, 2 * kt + s64);
      const float rf0 = __expf(Gtv - Mt0);
      const float rf1 = __expf(Gtv - Mt1);

      f32x16 sacc0 = {}, sacc1 = {};
      __builtin_amdgcn_s_setprio(1);
      #pragma unroll
      for (int ks = 0; ks < 8; ++ks) {
        sacc0 = MFMA_(kf[ks], qf0[ks], sacc0);
        sacc1 = MFMA_(kf[ks], qf1[ks], sacc1);
      }
      __builtin_amdgcn_s_setprio(0);

      const bool last = (kt == ktLast);
      f16x8 p00, p01, p10, p11;
      // repack t-block 0
      {
        float tsum = 0.f;
        uint32_t pk[8];
        #pragma unroll
        for (int rr = 0; rr < 8; ++rr) {
          float v0 = sacc0[2 * rr] * rf0;
          float v1 = sacc0[2 * rr + 1] * rf0;
          if (last) {
            int sl0 = 32 * w + ((2 * rr) & 3) + 8 * (rr >> 1) + 4 * hi;
            int bnd = tg0 - 128 * kt;
            if (sl0 > bnd) v0 = 0.f;
            if (sl0 + 1 > bnd) v1 = 0.f;
          }
          tsum += v0 + v1;
          pk[rr] = pkh(v0, v1);
        }
        rowsum0 += tsum + __shfl_xor(tsum, 32);
        uint32_t sw[8];
        #pragma unroll
        for (int rr = 0; rr < 8; ++rr) sw[rr] = __shfl_xor(pk[rr], 32);
        uint4 f0, f1;
        f0.x = hi ? sw[2] : pk[0];  f0.y = hi ? sw[3] : pk[1];
        f0.z = hi ? pk[2] : sw[0];  f0.w = hi ? pk[3] : sw[1];
        f1.x = hi ? sw[6] : pk[4];  f1.y = hi ? sw[7] : pk[5];
        f1.z = hi ? pk[6] : sw[4];  f1.w = hi ? pk[7] : sw[5];
        p00 = __builtin_bit_cast(f16x8, f0);
        p01 = __builtin_bit_cast(f16x8, f1);
      }
      // repack t-block 1
      {
        float tsum = 0.f;
        uint32_t pk[8];
        #pragma unroll
        for (int rr = 0; rr < 8; ++rr) {
          float v0 = sacc1[2 * rr] * rf1;
          float v1 = sacc1[2 * rr + 1] * rf1;
          if (last) {
            int sl0 = 32 * w + ((2 * rr) & 3) + 8 * (rr >> 1) + 4 * hi;
            int bnd = tg1 - 128 * kt;
            if (sl0 > bnd) v0 = 0.f;
            if (sl0 + 1 > bnd) v1 = 0.f;
          }
          tsum += v0 + v1;
          pk[rr] = pkh(v0, v1);
        }
        rowsum1 += tsum + __shfl_xor(tsum, 32);
        uint32_t sw[8];
        #pragma unroll
        for (int rr = 0; rr < 8; ++rr) sw[rr] = __shfl_xor(pk[rr], 32);
        uint4 f0, f1;
        f0.x = hi ? sw[2] : pk[0];  f0.y = hi ? sw[3] : pk[1];
        f0.z = hi ? pk[2] : sw[0];  f0.w = hi ? pk[3] : sw[1];
        f1.x = hi ? sw[6] : pk[4];  f1.y = hi ? sw[7] : pk[5];
        f1.z = hi ? pk[6] : sw[4];  f1.w = hi ? pk[7] : sw[5];
        p10 = __builtin_bit_cast(f16x8, f0);
        p11 = __builtin_bit_cast(f16x8, f1);
      }

      __builtin_amdgcn_s_setprio(1);
      #pragma unroll
      for (int df = 0; df < 4; ++df) {
        h0[df] = MFMA_(vf[df * 2 + 0], p00, h0[df]);
        h1[df] = MFMA_(vf[df * 2 + 0], p10, h1[df]);
        h0[df] = MFMA_(vf[df * 2 + 1], p01, h0[df]);
        h1[df] = MFMA_(vf[df * 2 + 1], p11, h1[df]);
      }
      __builtin_amdgcn_s_setprio(0);
    }

    // ---- epilogue: tree-combine 4 waves' partial h, wave 0 does LN+store ----
    if (w == 1 || w == 3) {
      const int base = (w == 1) ? 0 : 8192;
      #pragma unroll
      for (int df = 0; df < 4; ++df)
        #pragma unroll
        for (int r = 0; r < 16; ++r) {
          cb[base + (df * 16 + r) * 64 + lane]        = h0[df][r];
          cb[base + 4096 + (df * 16 + r) * 64 + lane] = h1[df][r];
        }
      const int rb = 16384 + ((w == 1) ? 0 : 128);
      cb[rb + lane] = rowsum0;
      cb[rb + 64 + lane] = rowsum1;
    }
    __syncthreads();
    if (w == 0 || w == 2) {
      const int base = (w == 0) ? 0 : 8192;
      #pragma unroll
      for (int df = 0; df < 4; ++df)
        #pragma unroll
        for (int r = 0; r < 16; ++r) {
          h0[df][r] += cb[base + (df * 16 + r) * 64 + lane];
          h1[df][r] += cb[base + 4096 + (df * 16 + r) * 64 + lane];
        }
      const int rb = 16384 + ((w == 0) ? 0 : 128);
      rowsum0 += cb[rb + lane];
      rowsum1 += cb[rb + 64 + lane];
    }
    __syncthreads();
    if (w == 2) {
      #pragma unroll
      for (int df = 0; df < 4; ++df)
        #pragma unroll
        for (int r = 0; r < 16; ++r) {
          cb[(df * 16 + r) * 64 + lane]        = h0[df][r];
          cb[4096 + (df * 16 + r) * 64 + lane] = h1[df][r];
        }
      cb[16384 + lane] = rowsum0;
      cb[16384 + 64 + lane] = rowsum1;
    }
    __syncthreads();
    if (w == 0) {
      #pragma unroll
      for (int df = 0; df < 4; ++df)
        #pragma unroll
        for (int r = 0; r < 16; ++r) {
          h0[df][r] += cb[(df * 16 + r) * 64 + lane];
          h1[df][r] += cb[4096 + (df * 16 + r) * 64 + lane];
        }
      rowsum0 += cb[16384 + lane];
      rowsum1 += cb[16384 + 64 + lane];

      #pragma unroll
      for (int tb = 0; tb < 2; ++tb) {
        const float rs = tb ? rowsum1 : rowsum0;
        const float em = tb ? em1 : em0;
        float n = fmaxf(fabsf(rs), em);
        float invn = 1.f / (n + 5e-5f);
        float s1 = 0.f, s2 = 0.f;
        #pragma unroll
        for (int df = 0; df < 4; ++df)
          #pragma unroll
          for (int r = 0; r < 16; ++r) {
            float xv = (tb ? h1[df][r] : h0[df][r]) * invn;
            if (tb) h1[df][r] = xv; else h0[df][r] = xv;
            s1 += xv; s2 += xv * xv;
          }
        s1 += __shfl_xor(s1, 32);
        s2 += __shfl_xor(s2, 32);
        float mu = s1 * (1.f / 128.f);
        float var = s2 * (1.f / 128.f) - mu * mu;
        float rstd = rsqrtf(var + 1e-3f);
        float* orow = out + ((size_t)(b * S_LEN) + 64 * j + 32 * tb + lo) * D_DIM + hh * DHEAD;
        #pragma unroll
        for (int df = 0; df < 4; ++df) {
          #pragma unroll
          for (int rq = 0; rq < 4; ++rq) {
            int dbase = 32 * df + 8 * rq + 4 * hi;
            float4 wv = *(const float4*)(ln_w + hh * DHEAD + dbase);
            float4 bv = *(const float4*)(ln_b + hh * DHEAD + dbase);
            float v0 = tb ? h1[df][rq * 4 + 0] : h0[df][rq * 4 + 0];
            float v1 = tb ? h1[df][rq * 4 + 1] : h0[df][rq * 4 + 1];
            float v2 = tb ? h1[df][rq * 4 + 2] : h0[df][rq * 4 + 2];
            float v3 = tb ? h1[df][rq * 4 + 3] : h0[df][rq * 4 + 3];
            float4 o;
            o.x = (v0 - mu) * rstd * (1.f + wv.x) + bv.x;
            o.y = (v1 - mu) * rstd * (1.f + wv.y) + bv.y;
            o.z = (v2 - mu) * rstd * (1.f + wv.z) + bv.z;
            o.w = (v3 - mu) * rstd * (1.f + wv.w) + bv.w;
            *(float4*)(orow + dbase) = o;
          }
        }
      }
    }
    __syncthreads();   // cb reused next queue item
  }
}

extern "C" void kernel_launch(void* const* d_in, const int* in_sizes, int n_in,
                              void* d_out, int out_size, void* d_ws, size_t ws_size,
                              hipStream_t stream) {
  (void)in_sizes; (void)n_in; (void)out_size; (void)ws_size;
  const float* q    = (const float*)d_in[0];
  const float* k    = (const float*)d_in[1];
  const float* v    = (const float*)d_in[2];
  const float* Wi   = (const float*)d_in[3];
  const float* bi   = (const float*)d_in[4];
  const float* Wf   = (const float*)d_in[5];
  const float* bf   = (const float*)d_in[6];
  const float* ln_w = (const float*)d_in[7];
  const float* ln_b = (const float*)d_in[8];

  char* wsb = (char*)d_ws;
  float* ipre = (float*)(wsb + 0);
  float* fpre = (float*)(wsb + 131072);
  float* garr = (float*)(wsb + 262144);
  float* Marr = (float*)(wsb + 393216);
  float* bsum = (float*)(wsb + 524288);
  float* Gt   = (float*)(wsb + 655360);       // 16*32 floats
  int*  qctr  = (int*)(wsb + 786432);          // 8 ints
  char* kh = wsb + 1048576;                    // 8MB
  char* vt = wsb + 1048576 + 8388608;          // 8MB

  hipMemsetAsync(qctr, 0, 8 * sizeof(int), stream);
  gate_kernel<<<2048, 256, 0, stream>>>(q, k, v, Wi, bi, Wf, bf, ipre, fpre);
  scan_kernel<<<16, 256, 0, stream>>>(ipre, fpre, garr, Marr, bsum, Gt);
  convert_kernel<<<dim3(8, 64), 256, 0, stream>>>(k, v, garr, Gt, kh, vt);
  attn_kernel<<<dim3(8, 64), 256, 0, stream>>>(q, kh, vt, Marr, bsum, Gt,
                                               ln_w, ln_b, (float*)d_out, qctr);
}

// Round 16
// 79.189 us; speedup vs baseline: 1.8353x; 1.8353x over previous
//
#include <hip/hip_runtime.h>
#include <cstddef>
#include <cstdint>

#define S_LEN 2048
#define D_DIM 512
#define NHEAD 4
#define DHEAD 128
#define BH_CNT 16
#define SCALE_QK 0.08838834764831845f

typedef _Float16 f16;
typedef _Float16 f16x8 __attribute__((ext_vector_type(8)));
typedef float f32x16 __attribute__((ext_vector_type(16)));

__device__ __forceinline__ unsigned pkh(float a, float b) {
  auto r = __builtin_amdgcn_cvt_pkrtz(a, b);   // __fp16 ext_vector_type(2)
  return __builtin_bit_cast(unsigned, r);
}

// ---------------- Kernel 1: gate preactivations ----------------
__global__ __launch_bounds__(256) void gate_kernel(
    const float* __restrict__ q, const float* __restrict__ k, const float* __restrict__ v,
    const float* __restrict__ Wi, const float* __restrict__ bi,
    const float* __restrict__ Wf, const float* __restrict__ bf,
    float* __restrict__ ipre, float* __restrict__ fpre)
{
  const int wave = threadIdx.x >> 6;
  const int lane = threadIdx.x & 63;
  const int pos  = blockIdx.x * 4 + wave;
  const int b = pos >> 11;
  const int s = pos & 2047;
  const float* qp = q + (size_t)pos * D_DIM;
  const float* kp = k + (size_t)pos * D_DIM;
  const float* vp = v + (size_t)pos * D_DIM;

  float acc[8] = {0.f,0.f,0.f,0.f,0.f,0.f,0.f,0.f};
  #pragma unroll
  for (int j = 0; j < 24; ++j) {
    int e = lane + (j << 6);
    float x;
    if (e < 512)       x = qp[e];
    else if (e < 1024) x = kp[e - 512];
    else               x = vp[e - 1024];
    #pragma unroll
    for (int h = 0; h < 4; ++h) {
      acc[h]     = fmaf(x, Wi[h * 1536 + e], acc[h]);
      acc[4 + h] = fmaf(x, Wf[h * 1536 + e], acc[4 + h]);
    }
  }
  #pragma unroll
  for (int off = 32; off > 0; off >>= 1) {
    #pragma unroll
    for (int a = 0; a < 8; ++a) acc[a] += __shfl_down(acc[a], off);
  }
  if (lane == 0) {
    #pragma unroll
    for (int h = 0; h < 4; ++h) {
      ipre[(size_t)(b * 4 + h) * S_LEN + s] = acc[h] + bi[h];
      fpre[(size_t)(b * 4 + h) * S_LEN + s] = acc[4 + h] + bf[h];
    }
  }
}

// ---------------- Kernel 2: single-pass register scans ----------------
__global__ __launch_bounds__(256) void scan_kernel(
    const float* __restrict__ ipre, const float* __restrict__ fpre,
    float* __restrict__ g_out, float* __restrict__ M_out,
    float* __restrict__ bsum_out, float* __restrict__ Gt_out)
{
  __shared__ float wsh[8];
  const int bh = blockIdx.x;
  const int tid = threadIdx.x, lane = tid & 63, wv = tid >> 6;
  const int base = tid * 8;
  const float* fp = fpre + (size_t)bh * S_LEN;
  const float* ip = ipre + (size_t)bh * S_LEN;

  float x[8], ls[8];
  float4 a0 = *(const float4*)(fp + base), a1 = *(const float4*)(fp + base + 4);
  x[0]=a0.x; x[1]=a0.y; x[2]=a0.z; x[3]=a0.w;
  x[4]=a1.x; x[5]=a1.y; x[6]=a1.z; x[7]=a1.w;
  float run = 0.f;
  #pragma unroll
  for (int i = 0; i < 8; ++i) {
    float lsv = fminf(x[i], 0.f) - log1pf(expf(-fabsf(x[i])));
    run += lsv; ls[i] = run;
  }
  float sc = run;
  #pragma unroll
  for (int off = 1; off < 64; off <<= 1) {
    float o = __shfl_up(sc, off);
    if (lane >= off) sc += o;
  }
  if (lane == 63) wsh[wv] = sc;
  __syncthreads();
  float woff = 0.f;
  #pragma unroll
  for (int u = 0; u < 4; ++u) if (u < wv) woff += wsh[u];
  const float ex = woff + (sc - run);

  float4 i0 = *(const float4*)(ip + base), i1 = *(const float4*)(ip + base + 4);
  float iv[8];
  iv[0]=i0.x; iv[1]=i0.y; iv[2]=i0.z; iv[3]=i0.w;
  iv[4]=i1.x; iv[5]=i1.y; iv[6]=i1.z; iv[7]=i1.w;
  float g[8], bc[8], pm[8];
  float runm = -3.0e38f;
  #pragma unroll
  for (int i = 0; i < 8; ++i) {
    bc[i] = ex + ls[i];
    g[i] = iv[i] - bc[i];
    runm = fmaxf(runm, g[i]);
    pm[i] = runm;
  }
  *(float4*)(bsum_out + (size_t)bh * S_LEN + base)     = make_float4(bc[0],bc[1],bc[2],bc[3]);
  *(float4*)(bsum_out + (size_t)bh * S_LEN + base + 4) = make_float4(bc[4],bc[5],bc[6],bc[7]);
  *(float4*)(g_out + (size_t)bh * S_LEN + base)        = make_float4(g[0],g[1],g[2],g[3]);
  *(float4*)(g_out + (size_t)bh * S_LEN + base + 4)    = make_float4(g[4],g[5],g[6],g[7]);

  float t8 = runm;
  t8 = fmaxf(t8, __shfl_xor(t8, 1));
  t8 = fmaxf(t8, __shfl_xor(t8, 2));
  t8 = fmaxf(t8, __shfl_xor(t8, 4));
  if ((tid & 7) == 0) Gt_out[bh * 32 + (tid >> 3)] = t8;

  float scm = runm;
  #pragma unroll
  for (int off = 1; off < 64; off <<= 1) {
    float o = __shfl_up(scm, off);
    if (lane >= off) scm = fmaxf(scm, o);
  }
  if (lane == 63) wsh[4 + wv] = scm;
  __syncthreads();
  float wmo = -3.0e38f;
  #pragma unroll
  for (int u = 0; u < 4; ++u) if (u < wv) wmo = fmaxf(wmo, wsh[4 + u]);
  float prev = __shfl_up(scm, 1);
  if (lane == 0) prev = -3.0e38f;
  const float exm = fmaxf(wmo, prev);
  float M[8];
  #pragma unroll
  for (int i = 0; i < 8; ++i) M[i] = fmaxf(exm, pm[i]);
  *(float4*)(M_out + (size_t)bh * S_LEN + base)     = make_float4(M[0],M[1],M[2],M[3]);
  *(float4*)(M_out + (size_t)bh * S_LEN + base + 4) = make_float4(M[4],M[5],M[6],M[7]);
}

// head-complementary bh pairing per XCD slot
__device__ __forceinline__ int pairA(int x) { return (x >> 1) * 4 + (x & 1); }
__device__ __forceinline__ int pairB(int x) { return (x >> 1) * 4 + 3 - (x & 1); }

// ---------------- Kernel 3: fp16 K/V conversion, fragment-linear, XCD-matched
__global__ __launch_bounds__(256) void convert_kernel(
    const float* __restrict__ k, const float* __restrict__ v,
    const float* __restrict__ g_arr, const float* __restrict__ Gt_arr,
    char* __restrict__ khat, char* __restrict__ vT)
{
  const int x = blockIdx.x, y = blockIdx.y;
  const int bh = (y < 32) ? pairA(x) : pairB(x);
  const int kt = (y < 32) ? y : (y - 32);
  const int b = bh >> 2, hh = bh & 3;
  const int tid = threadIdx.x;
  const size_t tb = (size_t)(bh * 32 + kt) * 16384;
  char* ktile = khat + tb;
  char* vtile = vT + tb;
  const float Gtv = Gt_arr[bh * 32 + kt];

  {
    const int dc8 = tid & 15;
    const int s4  = tid >> 4;
    const int ks = dc8 >> 1, hi = dc8 & 1;
    #pragma unroll
    for (int jj = 0; jj < 4; ++jj) {
      const int s = s4 + 16 * jj;
      const int sg = kt * 64 + s;
      const float cf = __expf(g_arr[(size_t)bh * S_LEN + sg] - Gtv);
      const int unit = (((s >> 5) * 8 + ks) * 2 + hi) * 32 + (s & 31);
      const float* kr = k + ((size_t)(b * S_LEN + sg)) * D_DIM + hh * DHEAD + dc8 * 8;
      float4 x0 = *(const float4*)kr;
      float4 x1 = *(const float4*)(kr + 4);
      uint4 u;
      u.x = pkh(x0.x * cf, x0.y * cf);
      u.y = pkh(x0.z * cf, x0.w * cf);
      u.z = pkh(x1.x * cf, x1.y * cf);
      u.w = pkh(x1.z * cf, x1.w * cf);
      *(uint4*)(ktile + unit * 16) = u;
    }
  }
  {
    const int d   = tid & 127;
    const int scg = tid >> 7;
    const int df = d >> 5, lo = d & 31;
    #pragma unroll
    for (int jj = 0; jj < 4; ++jj) {
      const int sc8 = scg + 2 * jj;
      const int c = sc8 >> 1, hi = sc8 & 1;
      const float* vr = v + ((size_t)(b * S_LEN + kt * 64 + sc8 * 8)) * D_DIM + hh * DHEAD + d;
      float vv[8];
      #pragma unroll
      for (int t = 0; t < 8; ++t) vv[t] = vr[(size_t)t * D_DIM];
      uint4 u;
      u.x = pkh(vv[0], vv[1]); u.y = pkh(vv[2], vv[3]);
      u.z = pkh(vv[4], vv[5]); u.w = pkh(vv[6], vv[7]);
      const int unit = ((df * 4 + c) * 2 + hi) * 32 + lo;
      *(uint4*)(vtile + unit * 16) = u;
    }
  }
}

#define MFMA_(a, b, c) __builtin_amdgcn_mfma_f32_32x32x16_f16(__builtin_bit_cast(f16x8, a), (b), (c), 0, 0, 0)

// ---------------- Kernel 4: 64-row-tile attention, 8 waves, per-XCD queue ----
// 256 blocks (1/CU), 512 threads = 8 waves = 2 waves/SIMD (TLP).
// Wave = (t-half th, s-quarter sq): ONE t-block of 32 -> h = 64 AGPR;
// arch ~148 + acc 64 = 212 <= 256 budget at launch_bounds(512,2): no spill.
// K/V each read once per t-half per step. Heavy-first atomic queue per XCD.
__global__ __launch_bounds__(512, 2) void attn_kernel(
    const float* __restrict__ q, const char* __restrict__ khat, const char* __restrict__ vT,
    const float* __restrict__ M_arr, const float* __restrict__ bs_arr,
    const float* __restrict__ Gt_arr,
    const float* __restrict__ ln_w, const float* __restrict__ ln_b,
    float* __restrict__ out, int* __restrict__ qctr)
{
  __shared__ float cb[16640];         // 4 regions x 4096 h-dump + 4x64 rowsum
  __shared__ int item_s;
  const int xcd = blockIdx.x;         // 0..7
  const int tid = threadIdx.x;
  const int w = tid >> 6, lane = tid & 63, lo = lane & 31, hi = lane >> 5;
  const int sq = w & 3, th = w >> 2;
  const int s64 = sq >> 1, s32 = sq & 1;
  const int lb16 = (hi * 32 + lo) * 16;

  for (;;) {
    if (tid == 0) item_s = atomicAdd(&qctr[xcd], 1);
    __syncthreads();
    const int item = item_s;
    __syncthreads();
    if (item >= 64) break;
    const int bh = (item & 1) ? pairB(xcd) : pairA(xcd);
    const int j  = 31 - (item >> 1);      // 64-row tile, heavy first
    const int b = bh >> 2, hh = bh & 3;

    const char* gk = khat + (size_t)bh * 524288;
    const char* gv = vT   + (size_t)bh * 524288;
    const float* Mb  = M_arr  + (size_t)bh * S_LEN;
    const float* bsb = bs_arr + (size_t)bh * S_LEN;
    const float GtReg = Gt_arr[bh * 32 + lo];

    const int tg = 64 * j + 32 * th + lo;
    const float Mt = Mb[tg];
    const float em = __expf(-(bsb[tg] + Mt));
    const float M0 = Mb[64 * j];
    const int ktLast = j >> 1;

    // ballot-based skip start
    int kts;
    {
      float ga = __shfl(GtReg, 2 * (lane & 15));
      float gb2 = __shfl(GtReg, 2 * (lane & 15) + 1);
      bool live = (lane < 16) && ((lane & 15) <= ktLast) &&
                  (fmaxf(ga, gb2) >= M0 - 25.f);
      unsigned long long mask = __ballot(live);
      kts = mask ? (__ffsll((long long)mask) - 1) : ktLast;
    }

    // Q fragments from fp32 q (once per item)
    f16x8 qf[8];
    {
      const float* qr = q + ((size_t)(b * S_LEN + tg)) * D_DIM + hh * DHEAD;
      #pragma unroll
      for (int ks = 0; ks < 8; ++ks) {
        const int d0 = ks * 16 + hi * 8;
        float4 x0 = *(const float4*)(qr + d0);
        float4 x1 = *(const float4*)(qr + d0 + 4);
        uint4 u;
        u.x = pkh(x0.x * SCALE_QK, x0.y * SCALE_QK);
        u.y = pkh(x0.z * SCALE_QK, x0.w * SCALE_QK);
        u.z = pkh(x1.x * SCALE_QK, x1.y * SCALE_QK);
        u.w = pkh(x1.z * SCALE_QK, x1.w * SCALE_QK);
        qf[ks] = __builtin_bit_cast(f16x8, u);
      }
    }

    f32x16 h[4] = {{},{},{},{}};   // d-blocks 0..3 for this wave's 32 t
    float rowsum = 0.f;

    for (int kt = kts; kt <= ktLast; ++kt) {
      const char* kbp = gk + (size_t)(2 * kt + s64) * 16384 + s32 * 8192 + lb16;
      uint4 kf[8];
      #pragma unroll
      for (int ks = 0; ks < 8; ++ks) kf[ks] = *(const uint4*)(kbp + ks * 1024);
      const char* vbp = gv + (size_t)(2 * kt + s64) * 16384 + 2 * s32 * 1024 + lb16;
      uint4 vf[8];
      #pragma unroll
      for (int df = 0; df < 4; ++df) {
        vf[df * 2 + 0] = *(const uint4*)(vbp + (df * 4 + 0) * 1024);
        vf[df * 2 + 1] = *(const uint4*)(vbp + (df * 4 + 1) * 1024);
      }

      const float Gtv = __shfl(GtReg, 2 * kt + s64);
      const float rf = __expf(Gtv - Mt);

      f32x16 sacc = {};
      __builtin_amdgcn_s_setprio(1);
      #pragma unroll
      for (int ks = 0; ks < 8; ++ks) sacc = MFMA_(kf[ks], qf[ks], sacc);
      __builtin_amdgcn_s_setprio(0);

      const bool last = (kt == ktLast);
      const int bnd = tg - 128 * kt;
      float tsum = 0.f;
      uint32_t pk[8];
      #pragma unroll
      for (int rr = 0; rr < 8; ++rr) {
        float v0 = sacc[2 * rr] * rf;
        float v1 = sacc[2 * rr + 1] * rf;
        if (last) {
          int sl0 = 32 * sq + ((2 * rr) & 3) + 8 * (rr >> 1) + 4 * hi;
          if (sl0 > bnd) v0 = 0.f;
          if (sl0 + 1 > bnd) v1 = 0.f;
        }
        tsum += v0 + v1;
        pk[rr] = pkh(v0, v1);
      }
      rowsum += tsum + __shfl_xor(tsum, 32);
      uint32_t sw[8];
      #pragma unroll
      for (int rr = 0; rr < 8; ++rr) sw[rr] = __shfl_xor(pk[rr], 32);
      uint4 f0, f1;
      f0.x = hi ? sw[2] : pk[0];  f0.y = hi ? sw[3] : pk[1];
      f0.z = hi ? pk[2] : sw[0];  f0.w = hi ? pk[3] : sw[1];
      f1.x = hi ? sw[6] : pk[4];  f1.y = hi ? sw[7] : pk[5];
      f1.z = hi ? pk[6] : sw[4];  f1.w = hi ? pk[7] : sw[5];
      f16x8 p0 = __builtin_bit_cast(f16x8, f0);
      f16x8 p1 = __builtin_bit_cast(f16x8, f1);

      __builtin_amdgcn_s_setprio(1);
      #pragma unroll
      for (int df = 0; df < 4; ++df) {
        h[df] = MFMA_(vf[df * 2 + 0], p0, h[df]);
        h[df] = MFMA_(vf[df * 2 + 1], p1, h[df]);
      }
      __builtin_amdgcn_s_setprio(0);
    }

    // ---- epilogue: per t-half, tree-combine 4 s-quarter waves via LDS ----
    // regions: (th*2 + r) * 4096 floats; rowsum at 16384 + (th*2+r)*64
    if (sq == 1 || sq == 3) {
      const int rg = th * 2 + (sq >> 1);
      #pragma unroll
      for (int df = 0; df < 4; ++df)
        #pragma unroll
        for (int r = 0; r < 16; ++r)
          cb[rg * 4096 + (df * 16 + r) * 64 + lane] = h[df][r];
      cb[16384 + rg * 64 + lane] = rowsum;
    }
    __syncthreads();
    if (sq == 0 || sq == 2) {
      const int rg = th * 2 + (sq >> 1);
      #pragma unroll
      for (int df = 0; df < 4; ++df)
        #pragma unroll
        for (int r = 0; r < 16; ++r)
          h[df][r] += cb[rg * 4096 + (df * 16 + r) * 64 + lane];
      rowsum += cb[16384 + rg * 64 + lane];
    }
    __syncthreads();
    if (sq == 2) {
      const int rg = th * 2 + 1;
      #pragma unroll
      for (int df = 0; df < 4; ++df)
        #pragma unroll
        for (int r = 0; r < 16; ++r)
          cb[rg * 4096 + (df * 16 + r) * 64 + lane] = h[df][r];
      cb[16384 + rg * 64 + lane] = rowsum;
    }
    __syncthreads();
    if (sq == 0) {
      const int rg = th * 2 + 1;
      #pragma unroll
      for (int df = 0; df < 4; ++df)
        #pragma unroll
        for (int r = 0; r < 16; ++r)
          h[df][r] += cb[rg * 4096 + (df * 16 + r) * 64 + lane];
      rowsum += cb[16384 + rg * 64 + lane];

      float n = fmaxf(fabsf(rowsum), em);
      float invn = 1.f / (n + 5e-5f);
      float s1 = 0.f, s2 = 0.f;
      #pragma unroll
      for (int df = 0; df < 4; ++df)
        #pragma unroll
        for (int r = 0; r < 16; ++r) {
          float xv = h[df][r] * invn;
          h[df][r] = xv;
          s1 += xv; s2 += xv * xv;
        }
      s1 += __shfl_xor(s1, 32);
      s2 += __shfl_xor(s2, 32);
      float mu = s1 * (1.f / 128.f);
      float var = s2 * (1.f / 128.f) - mu * mu;
      float rstd = rsqrtf(var + 1e-3f);
      float* orow = out + ((size_t)(b * S_LEN) + tg) * D_DIM + hh * DHEAD;
      #pragma unroll
      for (int df = 0; df < 4; ++df) {
        #pragma unroll
        for (int rq = 0; rq < 4; ++rq) {
          int dbase = 32 * df + 8 * rq + 4 * hi;
          float4 wv = *(const float4*)(ln_w + hh * DHEAD + dbase);
          float4 bv = *(const float4*)(ln_b + hh * DHEAD + dbase);
          float4 o;
          o.x = (h[df][rq * 4 + 0] - mu) * rstd * (1.f + wv.x) + bv.x;
          o.y = (h[df][rq * 4 + 1] - mu) * rstd * (1.f + wv.y) + bv.y;
          o.z = (h[df][rq * 4 + 2] - mu) * rstd * (1.f + wv.z) + bv.z;
          o.w = (h[df][rq * 4 + 3] - mu) * rstd * (1.f + wv.w) + bv.w;
          *(float4*)(orow + dbase) = o;
        }
      }
    }
    __syncthreads();   // cb reused next queue item
  }
}

extern "C" void kernel_launch(void* const* d_in, const int* in_sizes, int n_in,
                              void* d_out, int out_size, void* d_ws, size_t ws_size,
                              hipStream_t stream) {
  (void)in_sizes; (void)n_in; (void)out_size; (void)ws_size;
  const float* q    = (const float*)d_in[0];
  const float* k    = (const float*)d_in[1];
  const float* v    = (const float*)d_in[2];
  const float* Wi   = (const float*)d_in[3];
  const float* bi   = (const float*)d_in[4];
  const float* Wf   = (const float*)d_in[5];
  const float* bf   = (const float*)d_in[6];
  const float* ln_w = (const float*)d_in[7];
  const float* ln_b = (const float*)d_in[8];

  char* wsb = (char*)d_ws;
  float* ipre = (float*)(wsb + 0);
  float* fpre = (float*)(wsb + 131072);
  float* garr = (float*)(wsb + 262144);
  float* Marr = (float*)(wsb + 393216);
  float* bsum = (float*)(wsb + 524288);
  float* Gt   = (float*)(wsb + 655360);       // 16*32 floats
  int*  qctr  = (int*)(wsb + 786432);          // 8 ints
  char* kh = wsb + 1048576;                    // 8MB
  char* vt = wsb + 1048576 + 8388608;          // 8MB

  hipMemsetAsync(qctr, 0, 8 * sizeof(int), stream);
  gate_kernel<<<2048, 256, 0, stream>>>(q, k, v, Wi, bi, Wf, bf, ipre, fpre);
  scan_kernel<<<16, 256, 0, stream>>>(ipre, fpre, garr, Marr, bsum, Gt);
  convert_kernel<<<dim3(8, 64), 256, 0, stream>>>(k, v, garr, Gt, kh, vt);
  attn_kernel<<<dim3(8, 32), 512, 0, stream>>>(q, kh, vt, Marr, bsum, Gt,
                                               ln_w, ln_b, (float*)d_out, qctr);
}

// Round 17
// 78.032 us; speedup vs baseline: 1.8625x; 1.0148x over previous
//
#include <hip/hip_runtime.h>
#include <cstddef>
#include <cstdint>

#define S_LEN 2048
#define D_DIM 512
#define NHEAD 4
#define DHEAD 128
#define BH_CNT 16
#define SCALE_QK 0.08838834764831845f

typedef _Float16 f16;
typedef _Float16 f16x8 __attribute__((ext_vector_type(8)));
typedef float f32x16 __attribute__((ext_vector_type(16)));

__device__ __forceinline__ unsigned pkh(float a, float b) {
  auto r = __builtin_amdgcn_cvt_pkrtz(a, b);   // __fp16 ext_vector_type(2)
  return __builtin_bit_cast(unsigned, r);
}

// ---------------- Kernel 1: gate preactivations ----------------
__global__ __launch_bounds__(256) void gate_kernel(
    const float* __restrict__ q, const float* __restrict__ k, const float* __restrict__ v,
    const float* __restrict__ Wi, const float* __restrict__ bi,
    const float* __restrict__ Wf, const float* __restrict__ bf,
    float* __restrict__ ipre, float* __restrict__ fpre)
{
  const int wave = threadIdx.x >> 6;
  const int lane = threadIdx.x & 63;
  const int pos  = blockIdx.x * 4 + wave;
  const int b = pos >> 11;
  const int s = pos & 2047;
  const float* qp = q + (size_t)pos * D_DIM;
  const float* kp = k + (size_t)pos * D_DIM;
  const float* vp = v + (size_t)pos * D_DIM;

  float acc[8] = {0.f,0.f,0.f,0.f,0.f,0.f,0.f,0.f};
  #pragma unroll
  for (int j = 0; j < 24; ++j) {
    int e = lane + (j << 6);
    float x;
    if (e < 512)       x = qp[e];
    else if (e < 1024) x = kp[e - 512];
    else               x = vp[e - 1024];
    #pragma unroll
    for (int h = 0; h < 4; ++h) {
      acc[h]     = fmaf(x, Wi[h * 1536 + e], acc[h]);
      acc[4 + h] = fmaf(x, Wf[h * 1536 + e], acc[4 + h]);
    }
  }
  #pragma unroll
  for (int off = 32; off > 0; off >>= 1) {
    #pragma unroll
    for (int a = 0; a < 8; ++a) acc[a] += __shfl_down(acc[a], off);
  }
  if (lane == 0) {
    #pragma unroll
    for (int h = 0; h < 4; ++h) {
      ipre[(size_t)(b * 4 + h) * S_LEN + s] = acc[h] + bi[h];
      fpre[(size_t)(b * 4 + h) * S_LEN + s] = acc[4 + h] + bf[h];
    }
  }
}

// ---------------- Kernel 2: single-pass register scans ----------------
__global__ __launch_bounds__(256) void scan_kernel(
    const float* __restrict__ ipre, const float* __restrict__ fpre,
    float* __restrict__ g_out, float* __restrict__ M_out,
    float* __restrict__ bsum_out, float* __restrict__ Gt_out)
{
  __shared__ float wsh[8];
  const int bh = blockIdx.x;
  const int tid = threadIdx.x, lane = tid & 63, wv = tid >> 6;
  const int base = tid * 8;
  const float* fp = fpre + (size_t)bh * S_LEN;
  const float* ip = ipre + (size_t)bh * S_LEN;

  float x[8], ls[8];
  float4 a0 = *(const float4*)(fp + base), a1 = *(const float4*)(fp + base + 4);
  x[0]=a0.x; x[1]=a0.y; x[2]=a0.z; x[3]=a0.w;
  x[4]=a1.x; x[5]=a1.y; x[6]=a1.z; x[7]=a1.w;
  float run = 0.f;
  #pragma unroll
  for (int i = 0; i < 8; ++i) {
    float lsv = fminf(x[i], 0.f) - log1pf(expf(-fabsf(x[i])));
    run += lsv; ls[i] = run;
  }
  float sc = run;
  #pragma unroll
  for (int off = 1; off < 64; off <<= 1) {
    float o = __shfl_up(sc, off);
    if (lane >= off) sc += o;
  }
  if (lane == 63) wsh[wv] = sc;
  __syncthreads();
  float woff = 0.f;
  #pragma unroll
  for (int u = 0; u < 4; ++u) if (u < wv) woff += wsh[u];
  const float ex = woff + (sc - run);

  float4 i0 = *(const float4*)(ip + base), i1 = *(const float4*)(ip + base + 4);
  float iv[8];
  iv[0]=i0.x; iv[1]=i0.y; iv[2]=i0.z; iv[3]=i0.w;
  iv[4]=i1.x; iv[5]=i1.y; iv[6]=i1.z; iv[7]=i1.w;
  float g[8], bc[8], pm[8];
  float runm = -3.0e38f;
  #pragma unroll
  for (int i = 0; i < 8; ++i) {
    bc[i] = ex + ls[i];
    g[i] = iv[i] - bc[i];
    runm = fmaxf(runm, g[i]);
    pm[i] = runm;
  }
  *(float4*)(bsum_out + (size_t)bh * S_LEN + base)     = make_float4(bc[0],bc[1],bc[2],bc[3]);
  *(float4*)(bsum_out + (size_t)bh * S_LEN + base + 4) = make_float4(bc[4],bc[5],bc[6],bc[7]);
  *(float4*)(g_out + (size_t)bh * S_LEN + base)        = make_float4(g[0],g[1],g[2],g[3]);
  *(float4*)(g_out + (size_t)bh * S_LEN + base + 4)    = make_float4(g[4],g[5],g[6],g[7]);

  float t8 = runm;
  t8 = fmaxf(t8, __shfl_xor(t8, 1));
  t8 = fmaxf(t8, __shfl_xor(t8, 2));
  t8 = fmaxf(t8, __shfl_xor(t8, 4));
  if ((tid & 7) == 0) Gt_out[bh * 32 + (tid >> 3)] = t8;

  float scm = runm;
  #pragma unroll
  for (int off = 1; off < 64; off <<= 1) {
    float o = __shfl_up(scm, off);
    if (lane >= off) scm = fmaxf(scm, o);
  }
  if (lane == 63) wsh[4 + wv] = scm;
  __syncthreads();
  float wmo = -3.0e38f;
  #pragma unroll
  for (int u = 0; u < 4; ++u) if (u < wv) wmo = fmaxf(wmo, wsh[4 + u]);
  float prev = __shfl_up(scm, 1);
  if (lane == 0) prev = -3.0e38f;
  const float exm = fmaxf(wmo, prev);
  float M[8];
  #pragma unroll
  for (int i = 0; i < 8; ++i) M[i] = fmaxf(exm, pm[i]);
  *(float4*)(M_out + (size_t)bh * S_LEN + base)     = make_float4(M[0],M[1],M[2],M[3]);
  *(float4*)(M_out + (size_t)bh * S_LEN + base + 4) = make_float4(M[4],M[5],M[6],M[7]);
}

// head-complementary bh pairing per XCD slot
__device__ __forceinline__ int pairA(int x) { return (x >> 1) * 4 + (x & 1); }
__device__ __forceinline__ int pairB(int x) { return (x >> 1) * 4 + 3 - (x & 1); }

// ---------------- Kernel 3: fp16 K/V conversion, fragment-linear, XCD-matched
__global__ __launch_bounds__(256) void convert_kernel(
    const float* __restrict__ k, const float* __restrict__ v,
    const float* __restrict__ g_arr, const float* __restrict__ Gt_arr,
    char* __restrict__ khat, char* __restrict__ vT)
{
  const int x = blockIdx.x, y = blockIdx.y;
  const int bh = (y < 32) ? pairA(x) : pairB(x);
  const int kt = (y < 32) ? y : (y - 32);
  const int b = bh >> 2, hh = bh & 3;
  const int tid = threadIdx.x;
  const size_t tb = (size_t)(bh * 32 + kt) * 16384;
  char* ktile = khat + tb;
  char* vtile = vT + tb;
  const float Gtv = Gt_arr[bh * 32 + kt];

  {
    const int dc8 = tid & 15;
    const int s4  = tid >> 4;
    const int ks = dc8 >> 1, hi = dc8 & 1;
    #pragma unroll
    for (int jj = 0; jj < 4; ++jj) {
      const int s = s4 + 16 * jj;
      const int sg = kt * 64 + s;
      const float cf = __expf(g_arr[(size_t)bh * S_LEN + sg] - Gtv);
      const int unit = (((s >> 5) * 8 + ks) * 2 + hi) * 32 + (s & 31);
      const float* kr = k + ((size_t)(b * S_LEN + sg)) * D_DIM + hh * DHEAD + dc8 * 8;
      float4 x0 = *(const float4*)kr;
      float4 x1 = *(const float4*)(kr + 4);
      uint4 u;
      u.x = pkh(x0.x * cf, x0.y * cf);
      u.y = pkh(x0.z * cf, x0.w * cf);
      u.z = pkh(x1.x * cf, x1.y * cf);
      u.w = pkh(x1.z * cf, x1.w * cf);
      *(uint4*)(ktile + unit * 16) = u;
    }
  }
  {
    const int d   = tid & 127;
    const int scg = tid >> 7;
    const int df = d >> 5, lo = d & 31;
    #pragma unroll
    for (int jj = 0; jj < 4; ++jj) {
      const int sc8 = scg + 2 * jj;
      const int c = sc8 >> 1, hi = sc8 & 1;
      const float* vr = v + ((size_t)(b * S_LEN + kt * 64 + sc8 * 8)) * D_DIM + hh * DHEAD + d;
      float vv[8];
      #pragma unroll
      for (int t = 0; t < 8; ++t) vv[t] = vr[(size_t)t * D_DIM];
      uint4 u;
      u.x = pkh(vv[0], vv[1]); u.y = pkh(vv[2], vv[3]);
      u.z = pkh(vv[4], vv[5]); u.w = pkh(vv[6], vv[7]);
      const int unit = ((df * 4 + c) * 2 + hi) * 32 + lo;
      *(uint4*)(vtile + unit * 16) = u;
    }
  }
}

#define MFMA_(a, b, c) __builtin_amdgcn_mfma_f32_32x32x16_f16(__builtin_bit_cast(f16x8, a), (b), (c), 0, 0, 0)

// ---------------- Kernel 4: 64-row-tile attention, 8 waves, per-XCD queue ----
// 256 blocks (1/CU), 512 threads = 8 waves = 2 waves/SIMD.
// Wave = (t-half th, s-quarter sq). Dual QK accumulators -> 2 independent
// 4-deep MFMA chains per wave (4 chains/SIMD). Repack via permlane32_swap
// (VALU) instead of ds_bpermute. Rowsum cross-lane hoisted out of the loop.
__global__ __launch_bounds__(512, 2) void attn_kernel(
    const float* __restrict__ q, const char* __restrict__ khat, const char* __restrict__ vT,
    const float* __restrict__ M_arr, const float* __restrict__ bs_arr,
    const float* __restrict__ Gt_arr,
    const float* __restrict__ ln_w, const float* __restrict__ ln_b,
    float* __restrict__ out, int* __restrict__ qctr)
{
  __shared__ float cb[16640];         // 4 regions x 4096 h-dump + 4x64 rowsum
  __shared__ int item_s;
  const int xcd = blockIdx.x;         // 0..7
  const int tid = threadIdx.x;
  const int w = tid >> 6, lane = tid & 63, lo = lane & 31, hi = lane >> 5;
  const int sq = w & 3, th = w >> 2;
  const int s64 = sq >> 1, s32 = sq & 1;
  const int lb16 = (hi * 32 + lo) * 16;

  for (;;) {
    if (tid == 0) item_s = atomicAdd(&qctr[xcd], 1);
    __syncthreads();
    const int item = item_s;
    __syncthreads();
    if (item >= 64) break;
    const int bh = (item & 1) ? pairB(xcd) : pairA(xcd);
    const int j  = 31 - (item >> 1);      // 64-row tile, heavy first
    const int b = bh >> 2, hh = bh & 3;

    const char* gk = khat + (size_t)bh * 524288;
    const char* gv = vT   + (size_t)bh * 524288;
    const float* Mb  = M_arr  + (size_t)bh * S_LEN;
    const float* bsb = bs_arr + (size_t)bh * S_LEN;
    const float GtReg = Gt_arr[bh * 32 + lo];

    const int tg = 64 * j + 32 * th + lo;
    const float Mt = Mb[tg];
    const float em = __expf(-(bsb[tg] + Mt));
    const float M0 = Mb[64 * j];
    const int ktLast = j >> 1;

    // ballot-based skip start
    int kts;
    {
      float ga = __shfl(GtReg, 2 * (lane & 15));
      float gb2 = __shfl(GtReg, 2 * (lane & 15) + 1);
      bool live = (lane < 16) && ((lane & 15) <= ktLast) &&
                  (fmaxf(ga, gb2) >= M0 - 25.f);
      unsigned long long mask = __ballot(live);
      kts = mask ? (__ffsll((long long)mask) - 1) : ktLast;
    }

    // Q fragments from fp32 q (once per item)
    f16x8 qf[8];
    {
      const float* qr = q + ((size_t)(b * S_LEN + tg)) * D_DIM + hh * DHEAD;
      #pragma unroll
      for (int ks = 0; ks < 8; ++ks) {
        const int d0 = ks * 16 + hi * 8;
        float4 x0 = *(const float4*)(qr + d0);
        float4 x1 = *(const float4*)(qr + d0 + 4);
        uint4 u;
        u.x = pkh(x0.x * SCALE_QK, x0.y * SCALE_QK);
        u.y = pkh(x0.z * SCALE_QK, x0.w * SCALE_QK);
        u.z = pkh(x1.x * SCALE_QK, x1.y * SCALE_QK);
        u.w = pkh(x1.z * SCALE_QK, x1.w * SCALE_QK);
        qf[ks] = __builtin_bit_cast(f16x8, u);
      }
    }

    f32x16 h[4] = {{},{},{},{}};   // d-blocks 0..3 for this wave's 32 t
    float rowsum = 0.f;            // lane-local; cross-lane combine post-loop

    for (int kt = kts; kt <= ktLast; ++kt) {
      const char* kbp = gk + (size_t)(2 * kt + s64) * 16384 + s32 * 8192 + lb16;
      uint4 kf[8];
      #pragma unroll
      for (int ks = 0; ks < 8; ++ks) kf[ks] = *(const uint4*)(kbp + ks * 1024);
      const char* vbp = gv + (size_t)(2 * kt + s64) * 16384 + 2 * s32 * 1024 + lb16;
      uint4 vf[8];
      #pragma unroll
      for (int df = 0; df < 4; ++df) {
        vf[df * 2 + 0] = *(const uint4*)(vbp + (df * 4 + 0) * 1024);
        vf[df * 2 + 1] = *(const uint4*)(vbp + (df * 4 + 1) * 1024);
      }

      const float Gtv = __shfl(GtReg, 2 * kt + s64);
      const float rf = __expf(Gtv - Mt);

      // dual accumulators: two independent 4-deep MFMA chains
      f32x16 sa = {}, sb = {};
      __builtin_amdgcn_s_setprio(1);
      #pragma unroll
      for (int ks = 0; ks < 4; ++ks) {
        sa = MFMA_(kf[2 * ks],     qf[2 * ks],     sa);
        sb = MFMA_(kf[2 * ks + 1], qf[2 * ks + 1], sb);
      }
      __builtin_amdgcn_s_setprio(0);

      const bool last = (kt == ktLast);
      const int bnd = tg - 128 * kt;
      float tsum = 0.f;
      uint32_t pk[8];
      #pragma unroll
      for (int rr = 0; rr < 8; ++rr) {
        float v0 = (sa[2 * rr] + sb[2 * rr]) * rf;
        float v1 = (sa[2 * rr + 1] + sb[2 * rr + 1]) * rf;
        if (last) {
          int sl0 = 32 * sq + ((2 * rr) & 3) + 8 * (rr >> 1) + 4 * hi;
          if (sl0 > bnd) v0 = 0.f;
          if (sl0 + 1 > bnd) v1 = 0.f;
        }
        tsum += v0 + v1;
        pk[rr] = pkh(v0, v1);
      }
      rowsum += tsum;

      f16x8 p0, p1;
#if __has_builtin(__builtin_amdgcn_permlane32_swap)
      {
        auto r02 = __builtin_amdgcn_permlane32_swap(pk[0], pk[2], false, false);
        auto r13 = __builtin_amdgcn_permlane32_swap(pk[1], pk[3], false, false);
        auto r46 = __builtin_amdgcn_permlane32_swap(pk[4], pk[6], false, false);
        auto r57 = __builtin_amdgcn_permlane32_swap(pk[5], pk[7], false, false);
        uint4 f0, f1;
        f0.x = r02[0]; f0.y = r13[0]; f0.z = r02[1]; f0.w = r13[1];
        f1.x = r46[0]; f1.y = r57[0]; f1.z = r46[1]; f1.w = r57[1];
        p0 = __builtin_bit_cast(f16x8, f0);
        p1 = __builtin_bit_cast(f16x8, f1);
      }
#else
      {
        uint32_t sw[8];
        #pragma unroll
        for (int rr = 0; rr < 8; ++rr) sw[rr] = __shfl_xor(pk[rr], 32);
        uint4 f0, f1;
        f0.x = hi ? sw[2] : pk[0];  f0.y = hi ? sw[3] : pk[1];
        f0.z = hi ? pk[2] : sw[0];  f0.w = hi ? pk[3] : sw[1];
        f1.x = hi ? sw[6] : pk[4];  f1.y = hi ? sw[7] : pk[5];
        f1.z = hi ? pk[6] : sw[4];  f1.w = hi ? pk[7] : sw[5];
        p0 = __builtin_bit_cast(f16x8, f0);
        p1 = __builtin_bit_cast(f16x8, f1);
      }
#endif

      __builtin_amdgcn_s_setprio(1);
      #pragma unroll
      for (int df = 0; df < 4; ++df) {
        h[df] = MFMA_(vf[df * 2 + 0], p0, h[df]);
        h[df] = MFMA_(vf[df * 2 + 1], p1, h[df]);
      }
      __builtin_amdgcn_s_setprio(0);
    }

    rowsum += __shfl_xor(rowsum, 32);   // combine the two s-sub-halves once

    // ---- epilogue: per t-half, tree-combine 4 s-quarter waves via LDS ----
    if (sq == 1 || sq == 3) {
      const int rg = th * 2 + (sq >> 1);
      #pragma unroll
      for (int df = 0; df < 4; ++df)
        #pragma unroll
        for (int r = 0; r < 16; ++r)
          cb[rg * 4096 + (df * 16 + r) * 64 + lane] = h[df][r];
      cb[16384 + rg * 64 + lane] = rowsum;
    }
    __syncthreads();
    if (sq == 0 || sq == 2) {
      const int rg = th * 2 + (sq >> 1);
      #pragma unroll
      for (int df = 0; df < 4; ++df)
        #pragma unroll
        for (int r = 0; r < 16; ++r)
          h[df][r] += cb[rg * 4096 + (df * 16 + r) * 64 + lane];
      rowsum += cb[16384 + rg * 64 + lane];
    }
    __syncthreads();
    if (sq == 2) {
      const int rg = th * 2 + 1;
      #pragma unroll
      for (int df = 0; df < 4; ++df)
        #pragma unroll
        for (int r = 0; r < 16; ++r)
          cb[rg * 4096 + (df * 16 + r) * 64 + lane] = h[df][r];
      cb[16384 + rg * 64 + lane] = rowsum;
    }
    __syncthreads();
    if (sq == 0) {
      const int rg = th * 2 + 1;
      #pragma unroll
      for (int df = 0; df < 4; ++df)
        #pragma unroll
        for (int r = 0; r < 16; ++r)
          h[df][r] += cb[rg * 4096 + (df * 16 + r) * 64 + lane];
      rowsum += cb[16384 + rg * 64 + lane];

      float n = fmaxf(fabsf(rowsum), em);
      float invn = 1.f / (n + 5e-5f);
      float s1 = 0.f, s2 = 0.f;
      #pragma unroll
      for (int df = 0; df < 4; ++df)
        #pragma unroll
        for (int r = 0; r < 16; ++r) {
          float xv = h[df][r] * invn;
          h[df][r] = xv;
          s1 += xv; s2 += xv * xv;
        }
      s1 += __shfl_xor(s1, 32);
      s2 += __shfl_xor(s2, 32);
      float mu = s1 * (1.f / 128.f);
      float var = s2 * (1.f / 128.f) - mu * mu;
      float rstd = rsqrtf(var + 1e-3f);
      float* orow = out + ((size_t)(b * S_LEN) + tg) * D_DIM + hh * DHEAD;
      #pragma unroll
      for (int df = 0; df < 4; ++df) {
        #pragma unroll
        for (int rq = 0; rq < 4; ++rq) {
          int dbase = 32 * df + 8 * rq + 4 * hi;
          float4 wv = *(const float4*)(ln_w + hh * DHEAD + dbase);
          float4 bv = *(const float4*)(ln_b + hh * DHEAD + dbase);
          float4 o;
          o.x = (h[df][rq * 4 + 0] - mu) * rstd * (1.f + wv.x) + bv.x;
          o.y = (h[df][rq * 4 + 1] - mu) * rstd * (1.f + wv.y) + bv.y;
          o.z = (h[df][rq * 4 + 2] - mu) * rstd * (1.f + wv.z) + bv.z;
          o.w = (h[df][rq * 4 + 3] - mu) * rstd * (1.f + wv.w) + bv.w;
          *(float4*)(orow + dbase) = o;
        }
      }
    }
    __syncthreads();   // cb reused next queue item
  }
}

extern "C" void kernel_launch(void* const* d_in, const int* in_sizes, int n_in,
                              void* d_out, int out_size, void* d_ws, size_t ws_size,
                              hipStream_t stream) {
  (void)in_sizes; (void)n_in; (void)out_size; (void)ws_size;
  const float* q    = (const float*)d_in[0];
  const float* k    = (const float*)d_in[1];
  const float* v    = (const float*)d_in[2];
  const float* Wi   = (const float*)d_in[3];
  const float* bi   = (const float*)d_in[4];
  const float* Wf   = (const float*)d_in[5];
  const float* bf   = (const float*)d_in[6];
  const float* ln_w = (const float*)d_in[7];
  const float* ln_b = (const float*)d_in[8];

  char* wsb = (char*)d_ws;
  float* ipre = (float*)(wsb + 0);
  float* fpre = (float*)(wsb + 131072);
  float* garr = (float*)(wsb + 262144);
  float* Marr = (float*)(wsb + 393216);
  float* bsum = (float*)(wsb + 524288);
  float* Gt   = (float*)(wsb + 655360);       // 16*32 floats
  int*  qctr  = (int*)(wsb + 786432);          // 8 ints
  char* kh = wsb + 1048576;                    // 8MB
  char* vt = wsb + 1048576 + 8388608;          // 8MB

  hipMemsetAsync(qctr, 0, 8 * sizeof(int), stream);
  gate_kernel<<<2048, 256, 0, stream>>>(q, k, v, Wi, bi, Wf, bf, ipre, fpre);
  scan_kernel<<<16, 256, 0, stream>>>(ipre, fpre, garr, Marr, bsum, Gt);
  convert_kernel<<<dim3(8, 64), 256, 0, stream>>>(k, v, garr, Gt, kh, vt);
  attn_kernel<<<dim3(8, 32), 512, 0, stream>>>(q, kh, vt, Marr, bsum, Gt,
                                               ln_w, ln_b, (float*)d_out, qctr);
}